// Round 1
// baseline (197.285 us; speedup 1.0000x reference)
//
#include <hip/hip_runtime.h>
#include <math.h>

// Problem constants
#define B_   8
#define C_   64
#define O_   64
#define H_   128
#define W_   128
#define HW_  (H_ * W_)
#define KSZ  576            // C_*9 contraction length

typedef _Float16 f16x8 __attribute__((ext_vector_type(8)));
typedef float    f32x4 __attribute__((ext_vector_type(4)));

#define WPM_BYTES (18 * 4 * 64 * 8 * 2)   // 73728
#define WPA_BYTES (18 * 2 * 64 * 8 * 2)   // 36864
#define TB2_      (B_ * HW_ / 128)        // 1024 transpose tiles (128 px x 64 ch)

// ---------------------------------------------------------------------------
// Prep kernel (v2 — vectorized).
// Blocks [0,TB2_): LDS-tiled transpose x (B,C,H,W) fp32 -> (B,H,W,C) f16.
//   Read: float4 per lane; a wave covers 2 channel-rows x 512B contiguous.
//   8 iterations sweep all 64 channels of a 128-px strip.
//   LDS tile stride 68 f16; scalar f16 scatter-stores (conflicts cheap),
//   vector reads are 2-way-conflict only (free).
//   Write: each thread stores 32B of consecutive channels at one px; a wave
//   covers 4KB contiguous (perfect coalescing).
// Blocks [TB2_, TB2_+27): prepack weights into f16 MFMA A-fragment layout.
//   (unchanged layout: row = mt*16+(lane&15), k-local=(lane>>4)*8+j;
//    tap k=s>>1, cbase=(s&1)*32.)
// ---------------------------------------------------------------------------
__global__ __launch_bounds__(256) void prep_kernel(
    const float* __restrict__ x,
    const float* __restrict__ offw, const float* __restrict__ modw,
    const float* __restrict__ wgt,
    _Float16* __restrict__ xT, _Float16* __restrict__ wpM, _Float16* __restrict__ wpA)
{
    const int bi = blockIdx.x;
    if (bi < TB2_) {
        __shared__ _Float16 tile[128 * 68];
        const int tid = threadIdx.x;
        const int b      = bi >> 7;            // 128 tiles per batch
        const int pxbase = (bi & 127) * 128;

        // read: c = (tid>>5) + 8*r, px4 = (tid&31)*4  (float4 loads)
        const int px4   = (tid & 31) * 4;
        const int cbase = tid >> 5;
        const float* __restrict__ xp = x + (size_t)b * C_ * HW_ + pxbase;
#pragma unroll
        for (int r = 0; r < 8; ++r) {
            const int c = cbase + r * 8;
            const f32x4 v = *(const f32x4*)&xp[(size_t)c * HW_ + px4];
#pragma unroll
            for (int i = 0; i < 4; ++i)
                tile[(px4 + i) * 68 + c] = (_Float16)v[i];
        }
        __syncthreads();

        // write: px = tid>>1 (0..127), c0 = (tid&1)*32
        const int px = tid >> 1;
        const int c0 = (tid & 1) * 32;
        f16x8 w[4];
#pragma unroll
        for (int q = 0; q < 4; ++q)
#pragma unroll
            for (int j = 0; j < 8; ++j)
                w[q][j] = tile[px * 68 + c0 + q * 8 + j];
        _Float16* __restrict__ op = xT + ((size_t)b * HW_ + pxbase + px) * 64 + c0;
#pragma unroll
        for (int q = 0; q < 4; ++q)
            *(f16x8*)&op[q * 8] = w[q];
        return;
    }
    const int g = (bi - TB2_) * 256 + threadIdx.x;
    if (g < 18 * 4 * 64) {
        const int s = g >> 8, mt = (g >> 6) & 3, lane = g & 63;
        const int k = s >> 1, cb = (s & 1) * 32;
        const int o  = mt * 16 + (lane & 15);
        const int c0 = cb + (lane >> 4) * 8;
        f16x8 v;
#pragma unroll
        for (int j = 0; j < 8; ++j) v[j] = (_Float16)wgt[o * KSZ + (c0 + j) * 9 + k];
        *(f16x8*)&wpM[(size_t)g * 8] = v;
    } else if (g < 18 * 4 * 64 + 18 * 2 * 64) {
        const int u = g - 18 * 4 * 64;
        const int s = u >> 7, mt = (u >> 6) & 1, lane = u & 63;
        const int k = s >> 1, cb = (s & 1) * 32;
        const int t  = mt * 16 + (lane & 15);
        const int c0 = cb + (lane >> 4) * 8;
        f16x8 v;
#pragma unroll
        for (int j = 0; j < 8; ++j) {
            float w = 0.0f;
            if (t < 18)      w = offw[t * KSZ + (c0 + j) * 9 + k];
            else if (t < 27) w = modw[(t - 18) * KSZ + (c0 + j) * 9 + k];
            v[j] = (_Float16)w;
        }
        *(f16x8*)&wpA[(size_t)u * 8] = v;
    }
}

__device__ __forceinline__ f16x8 splat8(_Float16 h) {
    f16x8 v = {h, h, h, h, h, h, h, h};
    return v;
}

// ---------------------------------------------------------------------------
// Fused main kernel (v2 — occupancy-oriented).
// Block = 256 thr (4 waves) owns a 64-px half-row; each wave owns 16 px
// (one N-tile). Grid = B*H*2 = 2048 blocks. Halving per-wave gather state
// (4 loads in flight instead of 8, acc[4][1]) cuts VGPR pressure so the
// (256,4) clamp (4 waves/SIMD = 16 waves/CU, 4 blocks/CU, exactly 2 full
// residency passes) should hold without scratch spill — the old (256,4)
// spill was with the nt=2 working set.
// ---------------------------------------------------------------------------
__global__ __launch_bounds__(256, 4) void dcn_main_kernel(
    const _Float16* __restrict__ xT,    // (B, H, W, C) f16
    const _Float16* __restrict__ wpA,   // packed offset/mod weight frags
    const _Float16* __restrict__ wpM,   // packed main weight frags
    const float* __restrict__ offb,     // (18,)
    const float* __restrict__ modb,     // (9,)
    float* __restrict__ out)            // (B, O, H, W)
{
    __shared__ float params[4][27][16];   // [wave][t][px-in-wave-tile]

    const int tid  = threadIdx.x;
    const int lane = tid & 63;
    const int wave = tid >> 6;
    const int lq   = lane >> 4;
    const int ln   = lane & 15;

    const int bi   = blockIdx.x;
    const int b    = bi & 7;             // XCD-pinned batch
    const int r2   = bi >> 3;            // 0..255
    const int ho   = r2 >> 1;
    const int half = r2 & 1;
    const int wo   = half * 64 + wave * 16 + ln;   // this lane's output x

    const _Float16* __restrict__ xbT = xT + (size_t)b * HW_ * 64;

    // ---------------- Phase A: offset/modulator conv via MFMA ----------------
    f32x4 accA[2];
#pragma unroll
    for (int mt = 0; mt < 2; ++mt) accA[mt] = (f32x4){0.f, 0.f, 0.f, 0.f};

#pragma unroll
    for (int s = 0; s < 18; ++s) {
        const int k = s >> 1, cb = (s & 1) * 32;
        const int ki = k / 3, kj = k - ki * 3;
        const int y  = ho - 1 + ki;
        const int xx = wo - 1 + kj;
        const bool v = (y >= 0) && (y < H_) && (xx >= 0) && (xx < W_);
        f16x8 afA[2];
#pragma unroll
        for (int mt = 0; mt < 2; ++mt)
            afA[mt] = *(const f16x8*)&wpA[(size_t)((s * 2 + mt) * 64 + lane) * 8];
        f16x8 bfA;
        if (v) {
            bfA = *(const f16x8*)&xbT[((size_t)(y * W_ + xx)) * 64 + cb + lq * 8];
        } else {
            bfA = splat8((_Float16)0.0f);
        }
#pragma unroll
        for (int mt = 0; mt < 2; ++mt)
            accA[mt] = __builtin_amdgcn_mfma_f32_16x16x32_f16(afA[mt], bfA, accA[mt], 0, 0, 0);
    }

    // Epilogue A: D col = ln (px), row = mt*16 + lq*4 + r = param t.
#pragma unroll
    for (int mt = 0; mt < 2; ++mt)
#pragma unroll
        for (int r = 0; r < 4; ++r) {
            const int t = mt * 16 + lq * 4 + r;
            const float val = accA[mt][r];
            if (t < 18)      params[wave][t][ln] = val + offb[t];
            else if (t < 27) params[wave][t][ln] = 2.0f / (1.0f + expf(-(val + modb[t - 18])));
        }
    __syncthreads();

    // ---------------- Phase B: deformable gather + MFMA ----------------
    f32x4 acc[4];
#pragma unroll
    for (int mt = 0; mt < 4; ++mt) acc[mt] = (f32x4){0.f, 0.f, 0.f, 0.f};

#pragma unroll
    for (int s = 0; s < 18; ++s) {
        const int k = s >> 1, cb = (s & 1) * 32;
        const int ki = k / 3, kj = k - ki * 3;

        f16x8 af[4];
#pragma unroll
        for (int mt = 0; mt < 4; ++mt)
            af[mt] = *(const f16x8*)&wpM[(size_t)((s * 4 + mt) * 64 + lane) * 8];

        const float dy = params[wave][2 * k][ln];
        const float dx = params[wave][2 * k + 1][ln];
        const float mk = params[wave][18 + k][ln];

        const float ys = (float)(ho - 1 + ki) + dy;
        const float xs = (float)(wo - 1 + kj) + dx;
        const float y0f = floorf(ys), x0f = floorf(xs);
        const float wy = ys - y0f, wx = xs - x0f;
        const int y0 = (int)y0f, x0 = (int)x0f;
        const int y1 = y0 + 1,  x1 = x0 + 1;
        const bool vy0 = (y0 >= 0) && (y0 < H_);
        const bool vy1 = (y1 >= 0) && (y1 < H_);
        const bool vx0 = (x0 >= 0) && (x0 < W_);
        const bool vx1 = (x1 >= 0) && (x1 < W_);
        const int yc0 = min(max(y0, 0), H_ - 1);
        const int yc1 = min(max(y1, 0), H_ - 1);
        const int xc0 = min(max(x0, 0), W_ - 1);
        const int xc1 = min(max(x1, 0), W_ - 1);
        float w00 = (1.0f - wy) * (1.0f - wx) * mk; if (!(vy0 && vx0)) w00 = 0.0f;
        float w01 = (1.0f - wy) * wx          * mk; if (!(vy0 && vx1)) w01 = 0.0f;
        float w10 = wy          * (1.0f - wx) * mk; if (!(vy1 && vx0)) w10 = 0.0f;
        float w11 = wy          * wx          * mk; if (!(vy1 && vx1)) w11 = 0.0f;

        const int c0 = cb + lq * 8;
        const f16x8 a00 = *(const f16x8*)&xbT[((size_t)(yc0 * W_ + xc0)) * 64 + c0];
        const f16x8 a01 = *(const f16x8*)&xbT[((size_t)(yc0 * W_ + xc1)) * 64 + c0];
        const f16x8 a10 = *(const f16x8*)&xbT[((size_t)(yc1 * W_ + xc0)) * 64 + c0];
        const f16x8 a11 = *(const f16x8*)&xbT[((size_t)(yc1 * W_ + xc1)) * 64 + c0];

        const f16x8 w00v = splat8((_Float16)w00);
        const f16x8 w01v = splat8((_Float16)w01);
        const f16x8 w10v = splat8((_Float16)w10);
        const f16x8 w11v = splat8((_Float16)w11);

        f16x8 r = a00 * w00v;
        r = a01 * w01v + r;
        r = a10 * w10v + r;
        r = a11 * w11v + r;

#pragma unroll
        for (int mt = 0; mt < 4; ++mt)
            acc[mt] = __builtin_amdgcn_mfma_f32_16x16x32_f16(af[mt], r, acc[mt], 0, 0, 0);
    }

    // Epilogue B: D col = ln -> px, row = o.
    float* __restrict__ ob = out + (size_t)b * O_ * HW_ + (size_t)ho * W_;
#pragma unroll
    for (int mt = 0; mt < 4; ++mt)
#pragma unroll
        for (int r = 0; r < 4; ++r) {
            const int o = mt * 16 + lq * 4 + r;
            ob[(size_t)o * HW_ + wo] = acc[mt][r];
        }
}

extern "C" void kernel_launch(void* const* d_in, const int* in_sizes, int n_in,
                              void* d_out, int out_size, void* d_ws, size_t ws_size,
                              hipStream_t stream) {
    (void)in_sizes; (void)n_in; (void)out_size; (void)ws_size;
    const float* x    = (const float*)d_in[0];
    const float* offw = (const float*)d_in[1];
    const float* offb = (const float*)d_in[2];
    const float* modw = (const float*)d_in[3];
    const float* modb = (const float*)d_in[4];
    const float* wgt  = (const float*)d_in[5];
    float* out = (float*)d_out;

    _Float16* wpM = (_Float16*)d_ws;                                   // 73728 B
    _Float16* wpA = (_Float16*)((char*)d_ws + WPM_BYTES);              // 36864 B
    _Float16* xT  = (_Float16*)((char*)d_ws + WPM_BYTES + WPA_BYTES);  // 16.78 MB

    prep_kernel<<<TB2_ + 27, 256, 0, stream>>>(x, offw, modw, wgt, xT, wpM, wpA);
    dcn_main_kernel<<<B_ * H_ * 2, 256, 0, stream>>>(xT, wpA, wpM, offb, modb, out);
}

// Round 2
// 143.795 us; speedup vs baseline: 1.3720x; 1.3720x over previous
//
#include <hip/hip_runtime.h>
#include <math.h>

// Problem constants
#define B_   8
#define C_   64
#define O_   64
#define H_   128
#define W_   128
#define HW_  (H_ * W_)
#define KSZ  576            // C_*9 contraction length

typedef _Float16 f16x8 __attribute__((ext_vector_type(8)));
typedef float    f32x4 __attribute__((ext_vector_type(4)));

#define WPM_BYTES (18 * 4 * 64 * 8 * 2)   // 73728
#define WPA_BYTES (18 * 2 * 64 * 8 * 2)   // 36864
#define TB2_      (B_ * HW_ / 128)        // 1024 transpose tiles (128 px x 64 ch)

// ---------------------------------------------------------------------------
// Prep kernel (unchanged from v2 — vectorized transpose + weight prepack).
// ---------------------------------------------------------------------------
__global__ __launch_bounds__(256) void prep_kernel(
    const float* __restrict__ x,
    const float* __restrict__ offw, const float* __restrict__ modw,
    const float* __restrict__ wgt,
    _Float16* __restrict__ xT, _Float16* __restrict__ wpM, _Float16* __restrict__ wpA)
{
    const int bi = blockIdx.x;
    if (bi < TB2_) {
        __shared__ _Float16 tile[128 * 68];
        const int tid = threadIdx.x;
        const int b      = bi >> 7;
        const int pxbase = (bi & 127) * 128;

        const int px4   = (tid & 31) * 4;
        const int cbase = tid >> 5;
        const float* __restrict__ xp = x + (size_t)b * C_ * HW_ + pxbase;
#pragma unroll
        for (int r = 0; r < 8; ++r) {
            const int c = cbase + r * 8;
            const f32x4 v = *(const f32x4*)&xp[(size_t)c * HW_ + px4];
#pragma unroll
            for (int i = 0; i < 4; ++i)
                tile[(px4 + i) * 68 + c] = (_Float16)v[i];
        }
        __syncthreads();

        const int px = tid >> 1;
        const int c0 = (tid & 1) * 32;
        f16x8 w[4];
#pragma unroll
        for (int q = 0; q < 4; ++q)
#pragma unroll
            for (int j = 0; j < 8; ++j)
                w[q][j] = tile[px * 68 + c0 + q * 8 + j];
        _Float16* __restrict__ op = xT + ((size_t)b * HW_ + pxbase + px) * 64 + c0;
#pragma unroll
        for (int q = 0; q < 4; ++q)
            *(f16x8*)&op[q * 8] = w[q];
        return;
    }
    const int g = (bi - TB2_) * 256 + threadIdx.x;
    if (g < 18 * 4 * 64) {
        const int s = g >> 8, mt = (g >> 6) & 3, lane = g & 63;
        const int k = s >> 1, cb = (s & 1) * 32;
        const int o  = mt * 16 + (lane & 15);
        const int c0 = cb + (lane >> 4) * 8;
        f16x8 v;
#pragma unroll
        for (int j = 0; j < 8; ++j) v[j] = (_Float16)wgt[o * KSZ + (c0 + j) * 9 + k];
        *(f16x8*)&wpM[(size_t)g * 8] = v;
    } else if (g < 18 * 4 * 64 + 18 * 2 * 64) {
        const int u = g - 18 * 4 * 64;
        const int s = u >> 7, mt = (u >> 6) & 1, lane = u & 63;
        const int k = s >> 1, cb = (s & 1) * 32;
        const int t  = mt * 16 + (lane & 15);
        const int c0 = cb + (lane >> 4) * 8;
        f16x8 v;
#pragma unroll
        for (int j = 0; j < 8; ++j) {
            float w = 0.0f;
            if (t < 18)      w = offw[t * KSZ + (c0 + j) * 9 + k];
            else if (t < 27) w = modw[(t - 18) * KSZ + (c0 + j) * 9 + k];
            v[j] = (_Float16)w;
        }
        *(f16x8*)&wpA[(size_t)u * 8] = v;
    }
}

__device__ __forceinline__ f16x8 splat8(_Float16 h) {
    f16x8 v = {h, h, h, h, h, h, h, h};
    return v;
}

// ---------------------------------------------------------------------------
// Fused main kernel (v3 — LDS-windowed gather).
// r1 lesson: 4.3x occupancy at identical duration => TA/vector-memory
// address-issue bound on ~590K scattered dwordx4 gathers, not latency-bound.
// v3 stages a 7-row x 70-col x 64-ch f16 window (62.7KB LDS, XOR-swizzled
// 16B chunks) per 64-px half-row block; phase A and all bilinear corner
// reads become ds_read_b128. Window covers dy,dx in [-2,2); corners outside
// the window with nonzero weight (P ~ 1e-5 per sample) take a predicated
// per-lane global fallback, so correctness is data-independent.
// Params now broadcast via __shfl (no params LDS -> total LDS fits 64KB).
// Tap loop restructured k(9) x half(2): bilinear math once per k.
// ---------------------------------------------------------------------------
#define WROWS 7
#define WCOLS 70

#define PP_IDX(t) (((t) & 3) | (((t) >> 4) << 2))
#define PP_SRC(t) ((((t) & 15) >> 2) * 16)

__global__ __launch_bounds__(256, 2) void dcn_main_kernel(
    const _Float16* __restrict__ xT,    // (B, H, W, C) f16
    const _Float16* __restrict__ wpA,   // packed offset/mod weight frags
    const _Float16* __restrict__ wpM,   // packed main weight frags
    const float* __restrict__ offb,     // (18,)
    const float* __restrict__ modb,     // (9,)
    float* __restrict__ out)            // (B, O, H, W)
{
    __shared__ _Float16 win[WROWS * WCOLS * 64];   // 62720 B

    const int tid  = threadIdx.x;
    const int lane = tid & 63;
    const int wave = tid >> 6;
    const int lq   = lane >> 4;
    const int ln   = lane & 15;

    const int bi  = blockIdx.x;
    const int b   = bi & 7;             // XCD-pinned batch
    const int r2  = bi >> 3;            // 0..255
    const int ho  = r2 >> 1;
    const int x0b = (r2 & 1) * 64;
    const int pxw = wave * 16 + ln;     // px within half-row, 0..63
    const int wo  = x0b + pxw;          // this lane's output x

    const _Float16* __restrict__ xbT = xT + (size_t)b * HW_ * 64;

    // ---------------- Stage window: rows ho-3..ho+3, cols x0b-3..x0b+66 ----
    // (clamped-border replication; lookup slot = clamped_coord - origin is
    //  consistent with clamped staging by construction.)
#pragma unroll
    for (int it = 0; it < 16; ++it) {
        const int e = it * 256 + tid;
        if (e < WROWS * WCOLS * 8) {
            const int r   = e / (WCOLS * 8);
            const int rem = e - r * (WCOLS * 8);
            const int cx  = rem >> 3;
            const int q   = rem & 7;
            const int rs  = min(max(ho - 3 + r, 0), H_ - 1);
            const int cs  = min(max(x0b - 3 + cx, 0), W_ - 1);
            const f16x8 v = *(const f16x8*)&xbT[((size_t)(rs * W_ + cs)) * 64 + q * 8];
            *(f16x8*)&win[(r * WCOLS + cx) * 64 + ((q ^ (cx & 7)) * 8)] = v;
        }
    }
    __syncthreads();

    // ---------------- Phase A: offset/modulator conv via MFMA (LDS) --------
    f32x4 accA[2];
#pragma unroll
    for (int mt = 0; mt < 2; ++mt) accA[mt] = (f32x4){0.f, 0.f, 0.f, 0.f};

#pragma unroll
    for (int s = 0; s < 18; ++s) {
        const int k = s >> 1, h = s & 1;
        const int ki = k / 3, kj = k - ki * 3;
        const int y  = ho - 1 + ki;
        const int xx = wo - 1 + kj;
        const bool v = (y >= 0) && (y < H_) && (xx >= 0) && (xx < W_);
        f16x8 afA[2];
#pragma unroll
        for (int mt = 0; mt < 2; ++mt)
            afA[mt] = *(const f16x8*)&wpA[(size_t)((s * 2 + mt) * 64 + lane) * 8];
        const int sy = ki + 2;
        const int sx = pxw + kj + 2;
        const int chunk = h * 4 + lq;
        f16x8 bfA = *(const f16x8*)&win[(sy * WCOLS + sx) * 64 + ((chunk ^ (sx & 7)) * 8)];
        if (!v) bfA = splat8((_Float16)0.0f);
#pragma unroll
        for (int mt = 0; mt < 2; ++mt)
            accA[mt] = __builtin_amdgcn_mfma_f32_16x16x32_f16(afA[mt], bfA, accA[mt], 0, 0, 0);
    }

    // Params in registers: lane (lq,ln) owns t = mt*16 + lq*4 + r for px ln.
    float pp[8];
#pragma unroll
    for (int mt = 0; mt < 2; ++mt)
#pragma unroll
        for (int r = 0; r < 4; ++r) {
            const int t = mt * 16 + lq * 4 + r;
            const float val = accA[mt][r];
            float o = 0.0f;
            if (t < 18)      o = val + offb[t];
            else if (t < 27) o = 2.0f / (1.0f + expf(-(val + modb[t - 18])));
            pp[mt * 4 + r] = o;
        }

    // ---------------- Phase B: deformable gather (LDS) + MFMA --------------
    f32x4 acc[4];
#pragma unroll
    for (int mt = 0; mt < 4; ++mt) acc[mt] = (f32x4){0.f, 0.f, 0.f, 0.f};

#pragma unroll
    for (int k = 0; k < 9; ++k) {
        const int ki = k / 3, kj = k - ki * 3;

        // broadcast this px's params from owner lanes (intra-wave)
        const float dy = __shfl(pp[PP_IDX(2 * k)],     PP_SRC(2 * k) + ln, 64);
        const float dx = __shfl(pp[PP_IDX(2 * k + 1)], PP_SRC(2 * k + 1) + ln, 64);
        const float mk = __shfl(pp[PP_IDX(18 + k)],    PP_SRC(18 + k) + ln, 64);

        const float ys = (float)(ho - 1 + ki) + dy;
        const float xs = (float)(wo - 1 + kj) + dx;
        const float y0f = floorf(ys), x0f = floorf(xs);
        const float wy = ys - y0f, wx = xs - x0f;
        const int y0 = (int)y0f, x0 = (int)x0f;
        const int y1 = y0 + 1,  x1 = x0 + 1;
        const bool vy0 = (y0 >= 0) && (y0 < H_);
        const bool vy1 = (y1 >= 0) && (y1 < H_);
        const bool vx0 = (x0 >= 0) && (x0 < W_);
        const bool vx1 = (x1 >= 0) && (x1 < W_);
        const int yc0 = min(max(y0, 0), H_ - 1);
        const int yc1 = min(max(y1, 0), H_ - 1);
        const int xc0 = min(max(x0, 0), W_ - 1);
        const int xc1 = min(max(x1, 0), W_ - 1);
        float w00 = (1.0f - wy) * (1.0f - wx) * mk; if (!(vy0 && vx0)) w00 = 0.0f;
        float w01 = (1.0f - wy) * wx          * mk; if (!(vy0 && vx1)) w01 = 0.0f;
        float w10 = wy          * (1.0f - wx) * mk; if (!(vy1 && vx0)) w10 = 0.0f;
        float w11 = wy          * wx          * mk; if (!(vy1 && vx1)) w11 = 0.0f;

        // window slots (clamped-coord space)
        const int sy0 = yc0 - ho + 3, sy1 = yc1 - ho + 3;
        const int sx0 = xc0 - x0b + 3, sx1 = xc1 - x0b + 3;
        const bool oy0 = (unsigned)sy0 < WROWS, oy1 = (unsigned)sy1 < WROWS;
        const bool ox0 = (unsigned)sx0 < WCOLS, ox1 = (unsigned)sx1 < WCOLS;
        const bool ok00 = oy0 && ox0, ok01 = oy0 && ox1;
        const bool ok10 = oy1 && ox0, ok11 = oy1 && ox1;
        // safe (clamped) slots: garbage data only ever pairs with zero weight
        const int cy0 = min(max(sy0, 0), WROWS - 1), cy1 = min(max(sy1, 0), WROWS - 1);
        const int cx0 = min(max(sx0, 0), WCOLS - 1), cx1 = min(max(sx1, 0), WCOLS - 1);
        const int b00 = (cy0 * WCOLS + cx0) * 64, x7_00 = cx0 & 7;
        const int b01 = (cy0 * WCOLS + cx1) * 64, x7_01 = cx1 & 7;
        const int b10 = (cy1 * WCOLS + cx0) * 64, x7_10 = cx0 & 7;
        const int b11 = (cy1 * WCOLS + cx1) * 64, x7_11 = cx1 & 7;

        const f16x8 w00v = splat8((_Float16)w00);
        const f16x8 w01v = splat8((_Float16)w01);
        const f16x8 w10v = splat8((_Float16)w10);
        const f16x8 w11v = splat8((_Float16)w11);

#pragma unroll
        for (int h = 0; h < 2; ++h) {
            const int s = 2 * k + h;
            const int chunk = h * 4 + lq;
            const int c0 = h * 32 + lq * 8;

            f16x8 af[4];
#pragma unroll
            for (int mt = 0; mt < 4; ++mt)
                af[mt] = *(const f16x8*)&wpM[(size_t)((s * 4 + mt) * 64 + lane) * 8];

            f16x8 a00 = *(const f16x8*)&win[b00 + ((chunk ^ x7_00) * 8)];
            f16x8 a01 = *(const f16x8*)&win[b01 + ((chunk ^ x7_01) * 8)];
            f16x8 a10 = *(const f16x8*)&win[b10 + ((chunk ^ x7_10) * 8)];
            f16x8 a11 = *(const f16x8*)&win[b11 + ((chunk ^ x7_11) * 8)];

            // rare fallback: corner outside window but weight nonzero
            if (__builtin_expect(!ok00 && w00 != 0.0f, 0))
                a00 = *(const f16x8*)&xbT[((size_t)(yc0 * W_ + xc0)) * 64 + c0];
            if (__builtin_expect(!ok01 && w01 != 0.0f, 0))
                a01 = *(const f16x8*)&xbT[((size_t)(yc0 * W_ + xc1)) * 64 + c0];
            if (__builtin_expect(!ok10 && w10 != 0.0f, 0))
                a10 = *(const f16x8*)&xbT[((size_t)(yc1 * W_ + xc0)) * 64 + c0];
            if (__builtin_expect(!ok11 && w11 != 0.0f, 0))
                a11 = *(const f16x8*)&xbT[((size_t)(yc1 * W_ + xc1)) * 64 + c0];

            f16x8 r = a00 * w00v;
            r = a01 * w01v + r;
            r = a10 * w10v + r;
            r = a11 * w11v + r;

#pragma unroll
            for (int mt = 0; mt < 4; ++mt)
                acc[mt] = __builtin_amdgcn_mfma_f32_16x16x32_f16(af[mt], r, acc[mt], 0, 0, 0);
        }
    }

    // Epilogue B: D col = ln -> px, row = o.
    float* __restrict__ ob = out + (size_t)b * O_ * HW_ + (size_t)ho * W_;
#pragma unroll
    for (int mt = 0; mt < 4; ++mt)
#pragma unroll
        for (int r = 0; r < 4; ++r) {
            const int o = mt * 16 + lq * 4 + r;
            ob[(size_t)o * HW_ + wo] = acc[mt][r];
        }
}

extern "C" void kernel_launch(void* const* d_in, const int* in_sizes, int n_in,
                              void* d_out, int out_size, void* d_ws, size_t ws_size,
                              hipStream_t stream) {
    (void)in_sizes; (void)n_in; (void)out_size; (void)ws_size;
    const float* x    = (const float*)d_in[0];
    const float* offw = (const float*)d_in[1];
    const float* offb = (const float*)d_in[2];
    const float* modw = (const float*)d_in[3];
    const float* modb = (const float*)d_in[4];
    const float* wgt  = (const float*)d_in[5];
    float* out = (float*)d_out;

    _Float16* wpM = (_Float16*)d_ws;                                   // 73728 B
    _Float16* wpA = (_Float16*)((char*)d_ws + WPM_BYTES);              // 36864 B
    _Float16* xT  = (_Float16*)((char*)d_ws + WPM_BYTES + WPA_BYTES);  // 16.78 MB

    prep_kernel<<<TB2_ + 27, 256, 0, stream>>>(x, offw, modw, wgt, xT, wpM, wpA);
    dcn_main_kernel<<<B_ * H_ * 2, 256, 0, stream>>>(xT, wpA, wpM, offb, modb, out);
}